// Round 6
// baseline (6384.789 us; speedup 1.0000x reference)
//
#include <hip/hip_runtime.h>

typedef __bf16 bf16;
typedef __attribute__((ext_vector_type(8))) __bf16 bf16x8;
typedef __attribute__((ext_vector_type(4))) float f32x4;

// ---------------------------------------------------------------------------
// GEMM: out[M][1024](OUT) = A[M][1024](f32) @ W[1024][1024](f32) + bias(f32)
// (+ seg_emb gather if mode==1). Pure f32 VALU core: 16x16 threads, each an
// 8x8 micro-tile of a 128x128 block tile. f32 LDS staging (exact vs ref).
// ---------------------------------------------------------------------------
template <typename OUT>
__global__ __launch_bounds__(256, 2) void gemm_f32(
    const float* __restrict__ A, const float* __restrict__ W,
    const float* __restrict__ bias, OUT* __restrict__ out, int M, int mode,
    const int* __restrict__ segids, const float* __restrict__ segemb) {
  __shared__ __align__(16) float As[128][36];
  __shared__ __align__(16) float Bs[32][132];

  int tid = threadIdx.x;
  int tx = tid & 15, ty = tid >> 4;
  int nTilesM = M >> 7;
  int bm = blockIdx.x % nTilesM, bn = blockIdx.x / nTilesM;
  int m0 = bm * 128, n0 = bn * 128;

  float acc[8][8];
#pragma unroll
  for (int i = 0; i < 8; i++)
#pragma unroll
    for (int j = 0; j < 8; j++) acc[i][j] = 0.f;

  for (int k0 = 0; k0 < 1024; k0 += 32) {
    // A tile: [128 m][32 k] f32
#pragma unroll
    for (int u = tid; u < 512; u += 256) {
      int r = u >> 2, c = (u & 3) * 8;
      const float* src = A + (size_t)(m0 + r) * 1024 + k0 + c;
      *(f32x4*)&As[r][c] = *(const f32x4*)src;
      *(f32x4*)&As[r][c + 4] = *(const f32x4*)(src + 4);
    }
    // B tile: [32 k][128 n] f32
#pragma unroll
    for (int u = tid; u < 512; u += 256) {
      int r = u >> 4, cc = (u & 15) * 8;
      const float* src = W + (size_t)(k0 + r) * 1024 + n0 + cc;
      *(f32x4*)&Bs[r][cc] = *(const f32x4*)src;
      *(f32x4*)&Bs[r][cc + 4] = *(const f32x4*)(src + 4);
    }
    __syncthreads();
#pragma unroll
    for (int kk = 0; kk < 32; kk++) {
      float av[8], bv[8];
#pragma unroll
      for (int i = 0; i < 8; i++) av[i] = As[ty * 8 + i][kk];
#pragma unroll
      for (int j = 0; j < 8; j++) bv[j] = Bs[kk][tx * 8 + j];
#pragma unroll
      for (int i = 0; i < 8; i++)
#pragma unroll
        for (int j = 0; j < 8; j++) acc[i][j] += av[i] * bv[j];
    }
    __syncthreads();
  }

#pragma unroll
  for (int i = 0; i < 8; i++) {
    int m = m0 + ty * 8 + i;
    int seg = (mode == 1) ? segids[m] : 0;
#pragma unroll
    for (int j = 0; j < 8; j++) {
      int n = n0 + tx * 8 + j;
      float v = acc[i][j] + bias[n];
      if (mode == 1) v += segemb[(size_t)seg * 1024 + n];
      out[(size_t)m * 1024 + n] = (OUT)v;
    }
  }
}

// ---------------------------------------------------------------------------
// Naive exact-softmax attention + provenance. One block per (b,t); loop heads.
// Q/K f32 (exact scores); V bf16. Outputs: attended f32 (pre-Wo), prov f32.
// ---------------------------------------------------------------------------
__global__ __launch_bounds__(256) void attn_naive(
    const float* __restrict__ Qp, const float* __restrict__ Kp,
    const bf16* __restrict__ Vp, const int* __restrict__ mask,
    float* __restrict__ Oatt, float* __restrict__ prov) {
  int bt = blockIdx.x;
  int b = bt >> 9, t = bt & 511;
  __shared__ float qs[64];
  __shared__ float sc[4096];
  __shared__ float pacc[4096];
  __shared__ float red[256];
  __shared__ float po[4][64];
  int tid = threadIdx.x, wv = tid >> 6, lane = tid & 63;

  for (int s = tid; s < 4096; s += 256) pacc[s] = 0.f;
  const int* mrow = mask + (b << 12);

  for (int h = 0; h < 16; ++h) {
    __syncthreads();  // protect qs/sc/red/po reuse across h
    if (tid < 64) qs[tid] = Qp[((size_t)(b * 512 + t)) * 1024 + h * 64 + tid];
    __syncthreads();
    // scores (masked, scaled) — f32 exact
    for (int s = tid; s < 4096; s += 256) {
      const float* krow = Kp + ((size_t)((b << 12) + s)) * 1024 + h * 64;
      float d = 0.f;
#pragma unroll
      for (int kk = 0; kk < 64; kk += 4) {
        f32x4 kv = *(const f32x4*)(krow + kk);
#pragma unroll
        for (int j = 0; j < 4; ++j) d += qs[kk + j] * kv[j];
      }
      sc[s] = (mrow[s] != 0) ? d * 0.125f : -1.0e9f;
    }
    __syncthreads();
    // row max
    float mx = -3.0e38f;
    for (int s = tid; s < 4096; s += 256) mx = fmaxf(mx, sc[s]);
    red[tid] = mx;
    __syncthreads();
    for (int off = 128; off; off >>= 1) {
      if (tid < off) red[tid] = fmaxf(red[tid], red[tid + off]);
      __syncthreads();
    }
    float m = red[0];
    __syncthreads();
    // exp + sum
    float sm = 0.f;
    for (int s = tid; s < 4096; s += 256) {
      float p = __expf(sc[s] - m);
      sc[s] = p;
      sm += p;
    }
    red[tid] = sm;
    __syncthreads();
    for (int off = 128; off; off >>= 1) {
      if (tid < off) red[tid] += red[tid + off];
      __syncthreads();
    }
    float il = 1.0f / red[0];
    // provenance accumulate (same-thread stripes)
    for (int s = tid; s < 4096; s += 256) pacc[s] += sc[s] * il * 0.0625f;
    // PV: wave wv handles s-quarter, lane = d
    float o = 0.f;
    const bf16* vb = Vp + ((size_t)((b << 12) + wv * 1024)) * 1024 + h * 64 + lane;
    for (int s = 0; s < 1024; ++s) o += sc[wv * 1024 + s] * (float)vb[(size_t)s * 1024];
    po[wv][lane] = o;
    __syncthreads();
    if (tid < 64) {
      float oo = (po[0][tid] + po[1][tid] + po[2][tid] + po[3][tid]) * il;
      Oatt[((size_t)(b * 512 + t)) * 1024 + h * 64 + tid] = oo;
    }
  }
  __syncthreads();
  for (int s = tid; s < 4096; s += 256)
    prov[((size_t)(b * 512 + t)) * 4096 + s] = pacc[s];
}

// ---------------------------------------------------------------------------
extern "C" void kernel_launch(void* const* d_in, const int* in_sizes, int n_in,
                              void* d_out, int out_size, void* d_ws, size_t ws_size,
                              hipStream_t stream) {
  const float* query = (const float*)d_in[0];
  const float* key = (const float*)d_in[1];
  const float* value = (const float*)d_in[2];
  const int* amask = (const int*)d_in[3];
  const int* segid = (const int*)d_in[4];
  const float* Wq = (const float*)d_in[5];
  const float* bq = (const float*)d_in[6];
  const float* Wk = (const float*)d_in[7];
  const float* bk = (const float*)d_in[8];
  const float* Wv = (const float*)d_in[9];
  const float* bv = (const float*)d_in[10];
  const float* Wo = (const float*)d_in[11];
  const float* bo = (const float*)d_in[12];
  const float* semb = (const float*)d_in[13];

  char* ws = (char*)d_ws;
  float* Qp = (float*)ws;                       // 2048x1024 f32 = 8 MB
  float* Kp = (float*)(ws + (8ull << 20));      // 16384x1024 f32 = 64 MB
  bf16* Vp = (bf16*)(ws + (72ull << 20));       // 16384x1024 bf16 = 32 MB
  float* OatF = (float*)(ws + (104ull << 20));  // 2048x1024 f32 = 8 MB

  float* outAtt = (float*)d_out;                 // [4,512,1024] f32
  float* outProv = outAtt + (size_t)2048 * 1024; // [4,512,4096] f32

  gemm_f32<float><<<16 * 8, 256, 0, stream>>>(query, Wq, bq, Qp, 2048, 0, nullptr, nullptr);
  gemm_f32<float><<<128 * 8, 256, 0, stream>>>(key, Wk, bk, Kp, 16384, 1, segid, semb);
  gemm_f32<bf16><<<128 * 8, 256, 0, stream>>>(value, Wv, bv, Vp, 16384, 0, nullptr, nullptr);
  attn_naive<<<2048, 256, 0, stream>>>(Qp, Kp, Vp, amask, OatF, outProv);
  gemm_f32<float><<<16 * 8, 256, 0, stream>>>(OatF, Wo, bo, outAtt, 2048, 0, nullptr, nullptr);
}